// Round 18
// baseline (63.771 us; speedup 1.0000x reference)
//
#include <hip/hip_runtime.h>

#define SEQ 2048
#define BSZ 2
#define NHEAD 16
#define NBH (BSZ * NHEAD)   // 32
#define HDIM 64
#define QBLK 64
#define KVBLK 64
#define NQT (SEQ / QBLK)    // 32
#define ROWSTRIDE (BSZ * NHEAD * HDIM)

typedef __bf16 bf16x8 __attribute__((ext_vector_type(8)));
typedef __bf16 bf16x4 __attribute__((ext_vector_type(4)));
typedef float f32x4 __attribute__((ext_vector_type(4)));

#define AS1 __attribute__((address_space(1)))
#define AS3 __attribute__((address_space(3)))

// ---- fused pre-pass: K convert+swizzle / V convert+sigma+swizzle / Z frags ----
// blocks [0,2048): K; [2048,3072): V; [3072,3104): Z.  (verified round-13/15)
__global__ __launch_bounds__(256)
void conv_all(const float* __restrict__ Kg, const float* __restrict__ Vg,
              const float* __restrict__ PKVg, __bf16* __restrict__ Kb,
              __bf16* __restrict__ Vt, __bf16* __restrict__ Ztb) {
  __shared__ __bf16 tt[HDIM][72];
  const int b = blockIdx.x;
  const int tid = threadIdx.x;

  if (b < 2048) {
    // K fp32 [s][b][h][d] -> bf16 [bh][s][d_slotswz]; slot = (d>>3)^(s&7)
    const int t = b * 256 + tid;
    const int s = t >> 8;
    const int bh = (t >> 3) & 31;
    const int d8 = (t & 7) * 8;
    const float* src = Kg + (size_t)s * ROWSTRIDE + bh * HDIM + d8;
    const float4 a = *(const float4*)src;
    const float4 bb = *(const float4*)(src + 4);
    bf16x8 o = {(__bf16)a.x, (__bf16)a.y, (__bf16)a.z, (__bf16)a.w,
                (__bf16)bb.x, (__bf16)bb.y, (__bf16)bb.z, (__bf16)bb.w};
    const int slot = (d8 >> 3) ^ (s & 7);
    *(bf16x8*)(Kb + ((size_t)bh * SEQ + s) * HDIM + slot * 8) = o;
  } else if (b < 3072) {
    // V fp32 -> bf16 [bh][kb][dout][pos] tile-contiguous, sigma-permuted,
    // slot-swizzled (round-12 derivation).
    const int t = b - 2048;
    const int kb = t & 31, bh = t >> 5;
    {
      const int r = tid >> 2, c16 = (tid & 3) * 16;
#pragma unroll
      for (int i = 0; i < 4; ++i) {
        const float4 v = *(const float4*)(Vg + (size_t)(kb * 64 + r) * ROWSTRIDE +
                                          bh * HDIM + c16 + 4 * i);
        tt[c16 + 4 * i + 0][r] = (__bf16)v.x;
        tt[c16 + 4 * i + 1][r] = (__bf16)v.y;
        tt[c16 + 4 * i + 2][r] = (__bf16)v.z;
        tt[c16 + 4 * i + 3][r] = (__bf16)v.w;
      }
    }
    __syncthreads();
    {
      const int d = tid >> 2, c2 = (tid & 3) * 2;
#pragma unroll
      for (int k8 = 0; k8 < 2; ++k8) {
        const int s8 = c2 + k8;
        const int pbase = (s8 ^ (d & 7)) * 8;
        __bf16 ov[8];
#pragma unroll
        for (int j = 0; j < 8; ++j) {
          const int p = pbase + j;
          const int P = p >> 5, g = (p >> 3) & 3, jj = p & 7;
          ov[j] = tt[d][32 * P + 16 * (jj >> 2) + 4 * g + (jj & 3)];
        }
        *(bf16x8*)(Vt + (((size_t)bh * 32 + kb) * 64 + d) * 64 + s8 * 8) =
            *(const bf16x8*)ov;
      }
    }
  } else {
    // Z -> bf16 fragment-order [h][dj][c][lane][8]
    const int t = (b - 3072) * 256 + tid;
    const int lr = t & 15, lg = (t >> 4) & 3, c = (t >> 6) & 1;
    const int dj = (t >> 7) & 3, h = t >> 9;
    __bf16 o[8];
#pragma unroll
    for (int i = 0; i < 8; ++i)
      o[i] = (__bf16)PKVg[((size_t)h * 64 + 32 * c + 8 * lg + i) * 64 + dj * 16 + lr];
    *(bf16x8*)(Ztb + (size_t)t * 8) = *(const bf16x8*)o;
  }
}

// ---- main: round-15 base + cross-tile pipeline (QK(t+1) || PV(t)) ----
__global__ __launch_bounds__(256, 4)
void ntk_attn(const float* __restrict__ Qg, const __bf16* __restrict__ Kb,
              const __bf16* __restrict__ Vt, const float* __restrict__ PKg,
              const __bf16* __restrict__ Ztb, float* __restrict__ Og) {
  __shared__ __bf16 Ks[2][KVBLK * HDIM];    // 2 x 8 KB
  __shared__ __bf16 Vts[2][KVBLK * HDIM];   // 2 x 8 KB  -> 32 KB total

  const int tid = threadIdx.x;
  const int w = tid >> 6, l = tid & 63, lr = l & 15, lg = l >> 4;

  // balanced work swizzle: each CU's 4 round-robin blocks sum to ~62 tiles.
  const int ord = blockIdx.x;
  const int bh = ord & 31, h = bh & (NHEAD - 1);
  const int v = ord >> 5;
  const int bx = (v < 16) ? v : 47 - v;
  const int q0 = bx * QBLK;
  const int ntile = bx + 1;
  const int headoff = bh * HDIM;
  const __bf16* Kbh = Kb + (size_t)bh * SEQ * HDIM;
  const __bf16* Vbh = Vt + (size_t)bh * SEQ * HDIM;   // tile-contiguous

  // ---- async DMA staging: pure linear 8 KB copies (swizzle baked in src) ----
  auto stage = [&](int kb, int bb) {
    const char* gk = (const char*)Kbh + ((size_t)kb << 13) + (w << 11) + (l << 4);
    const char* gv = (const char*)Vbh + ((size_t)kb << 13) + (w << 11) + (l << 4);
    __bf16* lk = &Ks[bb][w << 10];
    __bf16* lv = &Vts[bb][w << 10];
    __builtin_amdgcn_global_load_lds((const AS1 unsigned*)gk,
                                     (AS3 unsigned*)lk, 16, 0, 0);
    __builtin_amdgcn_global_load_lds((const AS1 unsigned*)(gk + 1024),
                                     (AS3 unsigned*)(lk + 512), 16, 0, 0);
    __builtin_amdgcn_global_load_lds((const AS1 unsigned*)gv,
                                     (AS3 unsigned*)lv, 16, 0, 0);
    __builtin_amdgcn_global_load_lds((const AS1 unsigned*)(gv + 1024),
                                     (AS3 unsigned*)(lv + 512), 16, 0, 0);
  };

  stage(0, 0);   // in flight during the Q prologue

  // ---- Q fragments (scale 0.125/ln2 -> exp2 == exp) + phi(Q); m'=0 ----
  bf16x8 aq[2], pq[2];
  {
    const float* qp = Qg + (size_t)(q0 + w * 16 + lr) * ROWSTRIDE + headoff + lg * 8;
#pragma unroll
    for (int c = 0; c < 2; ++c) {
      const float4 x0 = *(const float4*)(qp + 32 * c);
      const float4 x1 = *(const float4*)(qp + 32 * c + 4);
      const float f[8] = {x0.x, x0.y, x0.z, x0.w, x1.x, x1.y, x1.z, x1.w};
#pragma unroll
      for (int i = 0; i < 8; ++i) {
        aq[c][i] = (__bf16)(f[i] * 0.18033688011112042f);  // 0.125/ln2
        const float xs = f[i] * 0.3535533905932738f;
        pq[c][i] = (__bf16)(xs > 0.f ? xs + 1.f : __expf(xs));
      }
    }
  }

  const f32x4 z4 = {0.f, 0.f, 0.f, 0.f};
  f32x4 oacc[4] = {z4, z4, z4, z4};
  float lsum = 0.f;                      // per-lane, q = lr
  const int qa = q0 + w * 16 + lr;
  const int sw = lr & 7;                 // read-side slot swizzle

  // fragment read helpers (slot-swizzled; sigma baked into V layout)
  bf16x8 kc[4][2];
  auto read_kc = [&](int bb) {
#pragma unroll
    for (int nj = 0; nj < 4; ++nj)
#pragma unroll
      for (int c = 0; c < 2; ++c)
        kc[nj][c] = *(const bf16x8*)&Ks[bb][(nj * 16 + lr) * 64 +
                                           (((4 * c + lg) ^ sw) << 3)];
  };

  // ---- prologue: QK(0) done before the loop; s4 carries across tiles ----
  f32x4 s4[4];
  __syncthreads();                       // drains DMA(0)
  read_kc(0);
  __builtin_amdgcn_s_setprio(1);
#pragma unroll
  for (int nj = 0; nj < 4; ++nj) {
    f32x4 acc = z4;
    acc = __builtin_amdgcn_mfma_f32_16x16x32_bf16(kc[nj][0], aq[0], acc, 0, 0, 0);
    acc = __builtin_amdgcn_mfma_f32_16x16x32_bf16(kc[nj][1], aq[1], acc, 0, 0, 0);
    s4[nj] = acc;
  }
  __builtin_amdgcn_s_setprio(0);
  if (ntile > 1) stage(1, 1);            // buf1 untouched so far: safe

  int cur = 0;
  // ==== pipelined main loop: on entry s4 = QK(kb); buf[cur] = tile kb ====
  for (int kb = 0; kb < ntile; ++kb) {
    // V^T fragments of tile kb (last reads of buf[cur])
    bf16x8 vv[2][4];
#pragma unroll
    for (int P = 0; P < 2; ++P)
#pragma unroll
      for (int dj = 0; dj < 4; ++dj)
        vv[P][dj] = *(const bf16x8*)&Vts[cur][(dj * 16 + lr) * 64 +
                                             (((4 * P + lg) ^ sw) << 3)];

    // P = exp2(S') = exp(S) (mask only the diagonal tile) — off MFMA path
    bf16x4 p4[4];
    const bool diag = (kb == bx);
    const int kv0 = kb * KVBLK;
#pragma unroll
    for (int nj = 0; nj < 4; ++nj) {
#pragma unroll
      for (int r = 0; r < 4; ++r) {
        float e;
        if (diag) {
          const int kabs = kv0 + 16 * nj + 4 * lg + r;
          e = (kabs <= qa) ? __builtin_amdgcn_exp2f(s4[nj][r]) : 0.f;
        } else {
          e = __builtin_amdgcn_exp2f(s4[nj][r]);
        }
        lsum += e;
        p4[nj][r] = (__bf16)e;
      }
    }

    const bool more = (kb + 1 < ntile);
    if (more) {
      __syncthreads();       // drains DMA(kb+1); all waves done reading buf[cur]
      read_kc(cur ^ 1);      // K fragments of tile kb+1
      if (kb + 2 < ntile) stage(kb + 2, cur);  // buf[cur] fully read: safe

      // one independent 16-MFMA cluster: QK(kb+1) (into s4) || PV(kb)
      __builtin_amdgcn_s_setprio(1);
#pragma unroll
      for (int nj = 0; nj < 4; ++nj) {
        f32x4 acc = z4;
        acc = __builtin_amdgcn_mfma_f32_16x16x32_bf16(kc[nj][0], aq[0], acc, 0, 0, 0);
        acc = __builtin_amdgcn_mfma_f32_16x16x32_bf16(kc[nj][1], aq[1], acc, 0, 0, 0);
        s4[nj] = acc;
      }
#pragma unroll
      for (int P = 0; P < 2; ++P) {
        const bf16x8 pa = __builtin_shufflevector(p4[2 * P], p4[2 * P + 1],
                                                  0, 1, 2, 3, 4, 5, 6, 7);
#pragma unroll
        for (int dj = 0; dj < 4; ++dj)
          oacc[dj] = __builtin_amdgcn_mfma_f32_16x16x32_bf16(pa, vv[P][dj],
                                                             oacc[dj], 0, 0, 0);
      }
      __builtin_amdgcn_s_setprio(0);
      cur ^= 1;
    } else {
      // tail: PV only
      __builtin_amdgcn_s_setprio(1);
#pragma unroll
      for (int P = 0; P < 2; ++P) {
        const bf16x8 pa = __builtin_shufflevector(p4[2 * P], p4[2 * P + 1],
                                                  0, 1, 2, 3, 4, 5, 6, 7);
#pragma unroll
        for (int dj = 0; dj < 4; ++dj)
          oacc[dj] = __builtin_amdgcn_mfma_f32_16x16x32_bf16(pa, vv[P][dj],
                                                             oacc[dj], 0, 0, 0);
      }
      __builtin_amdgcn_s_setprio(0);
    }
  }

  // ---- denominator: rowsum(q=lr) + phi_q.kk(q=lr), no LDS ----
  float den;
  {
    float pkk = 0.f;
#pragma unroll
    for (int c = 0; c < 2; ++c) {
      const float* kp = PKg + h * HDIM + 32 * c + 8 * lg;
      const float4 a = *(const float4*)kp;
      const float4 b = *(const float4*)(kp + 4);
      const float ka[8] = {a.x, a.y, a.z, a.w, b.x, b.y, b.z, b.w};
#pragma unroll
      for (int i = 0; i < 8; ++i)
        pkk += (float)pq[c][i] * fabsf(ka[i]);
    }
    pkk += __shfl_xor(pkk, 16);
    pkk += __shfl_xor(pkk, 32);
    float s = lsum;
    s += __shfl_xor(s, 16);
    s += __shfl_xor(s, 32);
    den = s + pkk;                       // valid for q = lr, all lanes
  }

  // ---- epilogue: phi_q @ Z (fragments straight from global), write ----
  f32x4 zacc[4] = {z4, z4, z4, z4};
  const __bf16* Zf = Ztb + (size_t)h * 4096;
  __builtin_amdgcn_s_setprio(1);
#pragma unroll
  for (int c = 0; c < 2; ++c) {
#pragma unroll
    for (int dj = 0; dj < 4; ++dj) {
      const bf16x8 bz = *(const bf16x8*)(Zf + ((dj * 2 + c) * 64 + l) * 8);
      zacc[dj] = __builtin_amdgcn_mfma_f32_16x16x32_bf16(pq[c], bz, zacc[dj], 0, 0, 0);
    }
  }
  __builtin_amdgcn_s_setprio(0);

#pragma unroll
  for (int r = 0; r < 4; ++r) {
    const float rd = 1.f / __shfl(den, lg * 4 + r);
    float* op = Og + (size_t)(q0 + w * 16 + lg * 4 + r) * ROWSTRIDE + headoff;
#pragma unroll
    for (int dj = 0; dj < 4; ++dj)
      op[dj * 16 + lr] = (oacc[dj][r] + zacc[dj][r]) * rd;
  }
}

extern "C" void kernel_launch(void* const* d_in, const int* in_sizes, int n_in,
                              void* d_out, int out_size, void* d_ws, size_t ws_size,
                              hipStream_t stream) {
  const float* Qg  = (const float*)d_in[0];
  const float* Kg  = (const float*)d_in[1];
  const float* Vg  = (const float*)d_in[2];
  const float* PKg  = (const float*)d_in[4];
  const float* PKVg = (const float*)d_in[5];
  float* Og = (float*)d_out;

  __bf16* Kb  = (__bf16*)d_ws;                      // [bh][s][d_swz]      8 MB
  __bf16* Vt  = Kb + (size_t)NBH * SEQ * HDIM;      // [bh][kb][d][s_swz]  8 MB
  __bf16* Ztb = Vt + (size_t)NBH * SEQ * HDIM;      // [h][frag]         128 KB

  conv_all<<<dim3(2048 + 1024 + 32), dim3(256), 0, stream>>>(Kg, Vg, PKVg,
                                                             Kb, Vt, Ztb);
  ntk_attn<<<dim3(NQT * NBH), dim3(256), 0, stream>>>(Qg, Kb, Vt, PKg, Ztb, Og);
}

// Round 19
// 45.260 us; speedup vs baseline: 1.4090x; 1.4090x over previous
//
#include <hip/hip_runtime.h>

#define SEQ 2048
#define BSZ 2
#define NHEAD 16
#define NBH (BSZ * NHEAD)   // 32
#define HDIM 64
#define QBLK 64
#define KVBLK 64
#define NQT (SEQ / QBLK)    // 32
#define ROWSTRIDE (BSZ * NHEAD * HDIM)

typedef __bf16 bf16x8 __attribute__((ext_vector_type(8)));
typedef __bf16 bf16x4 __attribute__((ext_vector_type(4)));
typedef float f32x4 __attribute__((ext_vector_type(4)));

#define AS1 __attribute__((address_space(1)))
#define AS3 __attribute__((address_space(3)))

// ---- fused pre-pass: K convert+swizzle / V convert+sigma+swizzle / Z frags ----
// blocks [0,2048): K; [2048,3072): V; [3072,3104): Z.  (verified round-13/15)
__global__ __launch_bounds__(256)
void conv_all(const float* __restrict__ Kg, const float* __restrict__ Vg,
              const float* __restrict__ PKVg, __bf16* __restrict__ Kb,
              __bf16* __restrict__ Vt, __bf16* __restrict__ Ztb) {
  __shared__ __bf16 tt[HDIM][72];
  const int b = blockIdx.x;
  const int tid = threadIdx.x;

  if (b < 2048) {
    // K fp32 [s][b][h][d] -> bf16 [bh][s][d_slotswz]; slot = (d>>3)^(s&7)
    const int t = b * 256 + tid;
    const int s = t >> 8;
    const int bh = (t >> 3) & 31;
    const int d8 = (t & 7) * 8;
    const float* src = Kg + (size_t)s * ROWSTRIDE + bh * HDIM + d8;
    const float4 a = *(const float4*)src;
    const float4 bb = *(const float4*)(src + 4);
    bf16x8 o = {(__bf16)a.x, (__bf16)a.y, (__bf16)a.z, (__bf16)a.w,
                (__bf16)bb.x, (__bf16)bb.y, (__bf16)bb.z, (__bf16)bb.w};
    const int slot = (d8 >> 3) ^ (s & 7);
    *(bf16x8*)(Kb + ((size_t)bh * SEQ + s) * HDIM + slot * 8) = o;
  } else if (b < 3072) {
    // V fp32 -> bf16 [bh][kb][dout][pos] tile-contiguous, sigma-permuted,
    // slot-swizzled (round-12 derivation).
    const int t = b - 2048;
    const int kb = t & 31, bh = t >> 5;
    {
      const int r = tid >> 2, c16 = (tid & 3) * 16;
#pragma unroll
      for (int i = 0; i < 4; ++i) {
        const float4 v = *(const float4*)(Vg + (size_t)(kb * 64 + r) * ROWSTRIDE +
                                          bh * HDIM + c16 + 4 * i);
        tt[c16 + 4 * i + 0][r] = (__bf16)v.x;
        tt[c16 + 4 * i + 1][r] = (__bf16)v.y;
        tt[c16 + 4 * i + 2][r] = (__bf16)v.z;
        tt[c16 + 4 * i + 3][r] = (__bf16)v.w;
      }
    }
    __syncthreads();
    {
      const int d = tid >> 2, c2 = (tid & 3) * 2;
#pragma unroll
      for (int k8 = 0; k8 < 2; ++k8) {
        const int s8 = c2 + k8;
        const int pbase = (s8 ^ (d & 7)) * 8;
        __bf16 ov[8];
#pragma unroll
        for (int j = 0; j < 8; ++j) {
          const int p = pbase + j;
          const int P = p >> 5, g = (p >> 3) & 3, jj = p & 7;
          ov[j] = tt[d][32 * P + 16 * (jj >> 2) + 4 * g + (jj & 3)];
        }
        *(bf16x8*)(Vt + (((size_t)bh * 32 + kb) * 64 + d) * 64 + s8 * 8) =
            *(const bf16x8*)ov;
      }
    }
  } else {
    // Z -> bf16 fragment-order [h][dj][c][lane][8]
    const int t = (b - 3072) * 256 + tid;
    const int lr = t & 15, lg = (t >> 4) & 3, c = (t >> 6) & 1;
    const int dj = (t >> 7) & 3, h = t >> 9;
    __bf16 o[8];
#pragma unroll
    for (int i = 0; i < 8; ++i)
      o[i] = (__bf16)PKVg[((size_t)h * 64 + 32 * c + 8 * lg + i) * 64 + dj * 16 + lr];
    *(bf16x8*)(Ztb + (size_t)t * 8) = *(const bf16x8*)o;
  }
}

// ---- main: round-15 proven structure, setprio removed, 4-way lsum ----
__global__ __launch_bounds__(256, 4)
void ntk_attn(const float* __restrict__ Qg, const __bf16* __restrict__ Kb,
              const __bf16* __restrict__ Vt, const float* __restrict__ PKg,
              const __bf16* __restrict__ Ztb, float* __restrict__ Og) {
  __shared__ __bf16 Ks[2][KVBLK * HDIM];    // 2 x 8 KB
  __shared__ __bf16 Vts[2][KVBLK * HDIM];   // 2 x 8 KB  -> 32 KB total

  const int tid = threadIdx.x;
  const int w = tid >> 6, l = tid & 63, lr = l & 15, lg = l >> 4;

  // balanced work swizzle: each CU's 4 round-robin blocks sum to ~62 tiles.
  const int ord = blockIdx.x;
  const int bh = ord & 31, h = bh & (NHEAD - 1);
  const int v = ord >> 5;
  const int bx = (v < 16) ? v : 47 - v;
  const int q0 = bx * QBLK;
  const int ntile = bx + 1;
  const int headoff = bh * HDIM;
  const __bf16* Kbh = Kb + (size_t)bh * SEQ * HDIM;
  const __bf16* Vbh = Vt + (size_t)bh * SEQ * HDIM;   // tile-contiguous

  // ---- async DMA staging: pure linear 8 KB copies (swizzle baked in src) ----
  auto stage = [&](int kb, int bb) {
    const char* gk = (const char*)Kbh + ((size_t)kb << 13) + (w << 11) + (l << 4);
    const char* gv = (const char*)Vbh + ((size_t)kb << 13) + (w << 11) + (l << 4);
    __bf16* lk = &Ks[bb][w << 10];
    __bf16* lv = &Vts[bb][w << 10];
    __builtin_amdgcn_global_load_lds((const AS1 unsigned*)gk,
                                     (AS3 unsigned*)lk, 16, 0, 0);
    __builtin_amdgcn_global_load_lds((const AS1 unsigned*)(gk + 1024),
                                     (AS3 unsigned*)(lk + 512), 16, 0, 0);
    __builtin_amdgcn_global_load_lds((const AS1 unsigned*)gv,
                                     (AS3 unsigned*)lv, 16, 0, 0);
    __builtin_amdgcn_global_load_lds((const AS1 unsigned*)(gv + 1024),
                                     (AS3 unsigned*)(lv + 512), 16, 0, 0);
  };

  stage(0, 0);   // issue first tile before the Q prologue (overlaps)

  // ---- Q fragments (scale 0.125/ln2 -> exp2 == exp) + phi(Q); m'=0 ----
  bf16x8 aq[2], pq[2];
  {
    const float* qp = Qg + (size_t)(q0 + w * 16 + lr) * ROWSTRIDE + headoff + lg * 8;
#pragma unroll
    for (int c = 0; c < 2; ++c) {
      const float4 x0 = *(const float4*)(qp + 32 * c);
      const float4 x1 = *(const float4*)(qp + 32 * c + 4);
      const float f[8] = {x0.x, x0.y, x0.z, x0.w, x1.x, x1.y, x1.z, x1.w};
#pragma unroll
      for (int i = 0; i < 8; ++i) {
        aq[c][i] = (__bf16)(f[i] * 0.18033688011112042f);  // 0.125/ln2
        const float xs = f[i] * 0.3535533905932738f;
        pq[c][i] = (__bf16)(xs > 0.f ? xs + 1.f : __expf(xs));
      }
    }
  }

  const f32x4 z4 = {0.f, 0.f, 0.f, 0.f};
  f32x4 oacc[4] = {z4, z4, z4, z4};
  float ls[4] = {0.f, 0.f, 0.f, 0.f};    // 4-way partial rowsum (per-lane q=lr)
  const int qa = q0 + w * 16 + lr;
  const int sw = lr & 7;                 // read-side slot swizzle

  __syncthreads();                       // tile 0 DMA drained
  int cur = 0;

  // ==== main loop: ONE barrier per tile, stage issued BEFORE compute ====
  for (int kb = 0; kb < ntile; ++kb) {
    const bool more = (kb + 1 < ntile);
    if (more) stage(kb + 1, cur ^ 1);

    // K fragments (slot-swizzled): 8 x ds_read_b128
    bf16x8 kc[4][2];
#pragma unroll
    for (int nj = 0; nj < 4; ++nj)
#pragma unroll
      for (int c = 0; c < 2; ++c)
        kc[nj][c] = *(const bf16x8*)&Ks[cur][(nj * 16 + lr) * 64 +
                                            (((4 * c + lg) ^ sw) << 3)];
    // V^T fragments (sigma-permuted + slot-swizzled): 8 x ds_read_b128
    bf16x8 vv[2][4];
#pragma unroll
    for (int P = 0; P < 2; ++P)
#pragma unroll
      for (int dj = 0; dj < 4; ++dj)
        vv[P][dj] = *(const bf16x8*)&Vts[cur][(dj * 16 + lr) * 64 +
                                             (((4 * P + lg) ^ sw) << 3)];

    // S'^T = K (Q*0.125/ln2)^T : lane holds S'[q=lr][k=kv0+16nj+4lg+r]
    f32x4 s4[4];
#pragma unroll
    for (int nj = 0; nj < 4; ++nj) {
      f32x4 acc = z4;
#pragma unroll
      for (int c = 0; c < 2; ++c)
        acc = __builtin_amdgcn_mfma_f32_16x16x32_bf16(kc[nj][c], aq[c], acc, 0, 0, 0);
      s4[nj] = acc;
    }

    // P = exp2(S') = exp(S) (mask only the diagonal tile), stays in regs
    bf16x4 p4[4];
    const bool diag = (kb == bx);
    const int kv0 = kb * KVBLK;
#pragma unroll
    for (int nj = 0; nj < 4; ++nj) {
#pragma unroll
      for (int r = 0; r < 4; ++r) {
        float e;
        if (diag) {
          const int kabs = kv0 + 16 * nj + 4 * lg + r;
          e = (kabs <= qa) ? __builtin_amdgcn_exp2f(s4[nj][r]) : 0.f;
        } else {
          e = __builtin_amdgcn_exp2f(s4[nj][r]);
        }
        ls[nj] += e;                     // independent chains per nj
        p4[nj][r] = (__bf16)e;
      }
    }

    // O += P V via sigma-permuted k32 MFMAs (A and B share sigma; exact)
#pragma unroll
    for (int P = 0; P < 2; ++P) {
      const bf16x8 pa = __builtin_shufflevector(p4[2 * P], p4[2 * P + 1],
                                                0, 1, 2, 3, 4, 5, 6, 7);
#pragma unroll
      for (int dj = 0; dj < 4; ++dj)
        oacc[dj] = __builtin_amdgcn_mfma_f32_16x16x32_bf16(pa, vv[P][dj],
                                                           oacc[dj], 0, 0, 0);
    }

    if (more) {
      __syncthreads();                   // drains next-tile DMA + buf reads
      cur ^= 1;
    }
  }

  // ---- denominator: rowsum(q=lr) + phi_q.kk(q=lr), no LDS ----
  float den;
  {
    float pkk = 0.f;
#pragma unroll
    for (int c = 0; c < 2; ++c) {
      const float* kp = PKg + h * HDIM + 32 * c + 8 * lg;
      const float4 a = *(const float4*)kp;
      const float4 b = *(const float4*)(kp + 4);
      const float ka[8] = {a.x, a.y, a.z, a.w, b.x, b.y, b.z, b.w};
#pragma unroll
      for (int i = 0; i < 8; ++i)
        pkk += (float)pq[c][i] * fabsf(ka[i]);
    }
    pkk += __shfl_xor(pkk, 16);
    pkk += __shfl_xor(pkk, 32);
    float s = (ls[0] + ls[1]) + (ls[2] + ls[3]);
    s += __shfl_xor(s, 16);
    s += __shfl_xor(s, 32);
    den = s + pkk;                       // valid for q = lr, all lanes
  }

  // ---- epilogue: phi_q @ Z (fragments straight from global), write ----
  f32x4 zacc[4] = {z4, z4, z4, z4};
  const __bf16* Zf = Ztb + (size_t)h * 4096;
#pragma unroll
  for (int c = 0; c < 2; ++c) {
#pragma unroll
    for (int dj = 0; dj < 4; ++dj) {
      const bf16x8 bz = *(const bf16x8*)(Zf + ((dj * 2 + c) * 64 + l) * 8);
      zacc[dj] = __builtin_amdgcn_mfma_f32_16x16x32_bf16(pq[c], bz, zacc[dj], 0, 0, 0);
    }
  }

#pragma unroll
  for (int r = 0; r < 4; ++r) {
    const float rd = 1.f / __shfl(den, lg * 4 + r);
    float* op = Og + (size_t)(q0 + w * 16 + lg * 4 + r) * ROWSTRIDE + headoff;
#pragma unroll
    for (int dj = 0; dj < 4; ++dj)
      op[dj * 16 + lr] = (oacc[dj][r] + zacc[dj][r]) * rd;
  }
}

extern "C" void kernel_launch(void* const* d_in, const int* in_sizes, int n_in,
                              void* d_out, int out_size, void* d_ws, size_t ws_size,
                              hipStream_t stream) {
  const float* Qg  = (const float*)d_in[0];
  const float* Kg  = (const float*)d_in[1];
  const float* Vg  = (const float*)d_in[2];
  const float* PKg  = (const float*)d_in[4];
  const float* PKVg = (const float*)d_in[5];
  float* Og = (float*)d_out;

  __bf16* Kb  = (__bf16*)d_ws;                      // [bh][s][d_swz]      8 MB
  __bf16* Vt  = Kb + (size_t)NBH * SEQ * HDIM;      // [bh][kb][d][s_swz]  8 MB
  __bf16* Ztb = Vt + (size_t)NBH * SEQ * HDIM;      // [h][frag]         128 KB

  conv_all<<<dim3(2048 + 1024 + 32), dim3(256), 0, stream>>>(Kg, Vg, PKVg,
                                                             Kb, Vt, Ztb);
  ntk_attn<<<dim3(NQT * NBH), dim3(256), 0, stream>>>(Qg, Kb, Vt, PKg, Ztb, Og);
}